// Round 3
// baseline (1016.777 us; speedup 1.0000x reference)
//
#include <hip/hip_runtime.h>
#include <hip/hip_bf16.h>
#include <stdint.h>

#define T_TOK 1024
#define H_DIM 2048
#define NEXP 8
#define IED 1408
#define ISD 5632

typedef __attribute__((ext_vector_type(8))) short s16x8;
typedef __attribute__((ext_vector_type(8))) unsigned short u16x8;
typedef __attribute__((ext_vector_type(4))) float f32x4;

__device__ __forceinline__ unsigned short f2bf(float f) {
  union { float f; unsigned u; } v; v.f = f;
  unsigned r = v.u + 0x7FFFu + ((v.u >> 16) & 1u);
  return (unsigned short)(r >> 16);
}

// ---------------- fp32 -> bf16 convert for hidden states ----------------
extern "C" __global__ void __launch_bounds__(256) k_cvt(
    const float* __restrict__ x, unsigned short* __restrict__ xb) {
  int i = (blockIdx.x * 256 + threadIdx.x) * 4;
  float4 v = *(const float4*)(x + i);
  ushort4 o;
  o.x = f2bf(v.x); o.y = f2bf(v.y); o.z = f2bf(v.z); o.w = f2bf(v.w);
  *(ushort4*)(xb + i) = o;
}

// ---------------- router: logits, softmax, top-4, shared gate ----------------
extern "C" __global__ void __launch_bounds__(256) k_router(
    const float* __restrict__ x, const float* __restrict__ wg,
    const float* __restrict__ wsg, int* __restrict__ counts,
    int* __restrict__ tlist, float* __restrict__ wlist,
    float* __restrict__ gate_sig) {
  const int lane = threadIdx.x & 63;
  const int t = blockIdx.x * 4 + (threadIdx.x >> 6);
  const float* xr = x + (size_t)t * H_DIM;
  float acc[8];
#pragma unroll
  for (int e = 0; e < 8; e++) acc[e] = 0.f;
  float sg = 0.f;
  for (int h = lane; h < H_DIM; h += 64) {
    float xv = xr[h];
    float4 w0 = *(const float4*)(wg + h * 8);
    float4 w1 = *(const float4*)(wg + h * 8 + 4);
    acc[0] += xv * w0.x; acc[1] += xv * w0.y; acc[2] += xv * w0.z; acc[3] += xv * w0.w;
    acc[4] += xv * w1.x; acc[5] += xv * w1.y; acc[6] += xv * w1.z; acc[7] += xv * w1.w;
    sg += xv * wsg[h];
  }
#pragma unroll
  for (int d = 32; d >= 1; d >>= 1) {
#pragma unroll
    for (int e = 0; e < 8; e++) acc[e] += __shfl_xor(acc[e], d, 64);
    sg += __shfl_xor(sg, d, 64);
  }
  if (lane == 0) {
    float m = acc[0];
#pragma unroll
    for (int e = 1; e < 8; e++) m = fmaxf(m, acc[e]);
    float p[8], s = 0.f;
#pragma unroll
    for (int e = 0; e < 8; e++) { p[e] = __expf(acc[e] - m); s += p[e]; }
    float inv = 1.f / s;
    bool used[8];
#pragma unroll
    for (int e = 0; e < 8; e++) used[e] = false;
    for (int j = 0; j < 4; j++) {
      int be = 0; float bv = -1e30f;
#pragma unroll
      for (int e = 0; e < 8; e++)
        if (!used[e] && acc[e] > bv) { bv = acc[e]; be = e; }
      used[be] = true;
      int slot = atomicAdd(counts + be, 1);
      tlist[be * T_TOK + slot] = t;
      wlist[be * T_TOK + slot] = p[be] * inv;
    }
    gate_sig[t] = 1.f / (1.f + __expf(-sg));
  }
}

// ---------------- staging / compute macros (static reg naming, rule #20) ----------------
#define LOADA(AR, kk)                                                     \
  do {                                                                    \
    _Pragma("unroll") for (int q = 0; q < 4; q++)                         \
        AR[q] = *(const u16x8*)(asrc[q] + (kk));                          \
  } while (0)

#define WRITEA(AR, OFFS)                                                  \
  do {                                                                    \
    _Pragma("unroll") for (int q = 0; q < 4; q++)                         \
        *(u16x8*)(adst[q] + (OFFS)) = AR[q];                              \
  } while (0)

#define LOADB(PG, PU, kk)                                                 \
  do {                                                                    \
    _Pragma("unroll") for (int i = 0; i < 8; i++) {                       \
      size_t ko = (size_t)((kk) + bkset + i) * (size_t)ldb;               \
      PG[i] = *(const float2*)(B0 + ko + bn);                             \
      PU[i] = *(const float2*)(B1 + ko + bn);                             \
    }                                                                     \
  } while (0)

#define CVTB(PG, PU, OFFS)                                                \
  do {                                                                    \
    _Pragma("unroll") for (int jj = 0; jj < 2; jj++) {                    \
      u16x8 pg, pu;                                                       \
      _Pragma("unroll") for (int i = 0; i < 8; i++) {                     \
        pg[i] = f2bf(jj ? PG[i].y : PG[i].x);                             \
        pu[i] = f2bf(jj ? PU[i].y : PU[i].x);                             \
      }                                                                   \
      *(u16x8*)(bwr[0][jj] + (OFFS)) = pg;                                \
      *(u16x8*)(bwr[1][jj] + (OFFS)) = pu;                                \
    }                                                                     \
  } while (0)

#define COMPUTE(OFFS)                                                     \
  do {                                                                    \
    const unsigned short* ab = a_lds + (OFFS);                            \
    const unsigned short* bb = b_lds + (OFFS);                            \
    __builtin_amdgcn_s_setprio(1);                                        \
    _Pragma("unroll") for (int ks = 0; ks < 2; ks++) {                    \
      int kc = ks * 4 + (lane >> 4);                                      \
      s16x8 afr[4];                                                       \
      _Pragma("unroll") for (int m = 0; m < 4; m++) {                     \
        int r = wm * 64 + m * 16 + (lane & 15);                           \
        afr[m] = *(const s16x8*)&ab[r * 64 + ((kc ^ (r & 7)) * 8)];       \
      }                                                                   \
      _Pragma("unroll") for (int nf = 0; nf < 4; nf++) {                  \
        int rb_;                                                          \
        if constexpr (MODE < 2) rb_ = wn * 32 + (nf & 1) * 16 + (nf >> 1) * 64; \
        else rb_ = wn * 64 + nf * 16;                                     \
        rb_ += (lane & 15);                                               \
        s16x8 bfr = *(const s16x8*)&bb[rb_ * 64 + ((kc ^ (rb_ & 7)) * 8)]; \
        _Pragma("unroll") for (int m = 0; m < 4; m++)                     \
            acc[m][nf] = __builtin_amdgcn_mfma_f32_16x16x32_bf16(         \
                afr[m], bfr, acc[m][nf], 0, 0, 0);                        \
      }                                                                   \
    }                                                                     \
    __builtin_amdgcn_s_setprio(0);                                        \
  } while (0)

// Raw barrier: lgkmcnt(0) for LDS-write visibility, NO vmcnt drain —
// in-flight global loads for tile u+2 survive the barrier.
#define PHASE_BAR()                                                       \
  do {                                                                    \
    __builtin_amdgcn_sched_barrier(0);                                    \
    asm volatile("s_waitcnt lgkmcnt(0)" ::: "memory");                    \
    __builtin_amdgcn_s_barrier();                                         \
    __builtin_amdgcn_sched_barrier(0);                                    \
  } while (0)

// ---------------- unified MFMA GEMM, raw-barrier pipelined, XCD-grouped ----------------
// MODE 0: shared gu   MODE 1: expert gu   MODE 2: shared down   MODE 3: expert down
template <int MODE>
__global__ void __launch_bounds__(256, 2) k_mm(
    const unsigned short* __restrict__ Abase, const float* __restrict__ Bbase,
    unsigned short* __restrict__ actout, float* __restrict__ out,
    const int* __restrict__ counts, const int* __restrict__ tlist,
    const float* __restrict__ wlist, const float* __restrict__ gate_sig) {
  const int tid = threadIdx.x;
  const int lane = tid & 63;
  const int wid = tid >> 6;
  const int wm = wid >> 1, wn = wid & 1;

  // XCD-grouped decode: xcd = b%8 owns P/8 consecutive B-panels; mtile fastest.
  constexpr int P = (MODE == 0) ? 88 : (MODE == 1) ? 176 : (MODE == 2) ? 64 : 128;
  const int b = blockIdx.x;
  const int xcd = b & 7;
  const int j = b >> 3;
  const int panel = xcd * (P >> 3) + (j >> 3);
  const int mtile = j & 7;
  int ntile = 0, z = 0, e = 0;
  if constexpr (MODE == 0) { ntile = panel; }
  else if constexpr (MODE == 1) { e = panel & 7; ntile = panel >> 3; }
  else if constexpr (MODE == 2) { ntile = panel >> 2; z = panel & 3; }
  else { e = panel & 7; ntile = panel >> 3; }

  int count = T_TOK, kbeg = 0, kend = 0, lda = 0, ldb = 0, IK = 0;
  const unsigned short* A = Abase;
  const float* B0 = nullptr; const float* B1 = nullptr;
  const int* tl = nullptr; const float* wl = nullptr;

  if constexpr (MODE == 0) {
    lda = H_DIM; kend = H_DIM; ldb = 2 * ISD; IK = ISD;
    B0 = Bbase + ntile * 64; B1 = Bbase + ISD + ntile * 64;
  } else if constexpr (MODE == 1) {
    count = counts[e];
    if (mtile * 128 >= count) return;
    lda = H_DIM; kend = H_DIM; ldb = 2 * IED; IK = IED;
    const float* Bw = Bbase + (size_t)e * H_DIM * (2 * IED);
    B0 = Bw + ntile * 64; B1 = Bw + IED + ntile * 64;
    tl = tlist + e * T_TOK; wl = wlist + e * T_TOK;
    actout += (size_t)e * T_TOK * IED;
  } else if constexpr (MODE == 2) {
    lda = ISD; kbeg = z * 1408; kend = kbeg + 1408; ldb = H_DIM; IK = H_DIM;
    B0 = Bbase + ntile * 128; B1 = Bbase + ntile * 128 + 64;
  } else {
    count = counts[e];
    if (mtile * 128 >= count) return;
    lda = IED; kend = IED; ldb = H_DIM; IK = H_DIM;
    B0 = Bbase + (size_t)e * IED * H_DIM + ntile * 128;
    B1 = B0 + 64;
    A = Abase + (size_t)e * T_TOK * IED;
    tl = tlist + e * T_TOK;
  }

  __shared__ unsigned short a_lds[2 * 8192];
  __shared__ unsigned short b_lds[2 * 8192];

  // A staging addresses (reg-staged; swizzle on LDS dest now)
  const unsigned short* asrc[4];
  unsigned short* adst[4];
#pragma unroll
  for (int q = 0; q < 4; q++) {
    int row = wid * 32 + q * 8 + (lane >> 3);
    int rowg = mtile * 128 + row;
    int arow = rowg;
    if constexpr (MODE == 1) arow = tl[rowg];  // padding slots hold 0 (memset)
    asrc[q] = A + (size_t)arow * lda + (lane & 7) * 8;
    adst[q] = &a_lds[row * 64 + (((lane & 7) ^ (row & 7)) * 8)];
  }

  // B staging geometry
  const int bn = (tid & 31) * 2;
  const int bkset = ((tid >> 5) & 7) * 8;
  const int bkc = (tid >> 5) & 7;
  unsigned short* bwr[2][2];
#pragma unroll
  for (int h = 0; h < 2; h++)
#pragma unroll
    for (int jj = 0; jj < 2; jj++) {
      int r = h * 64 + bn + jj;
      bwr[h][jj] = &b_lds[r * 64 + ((bkc ^ (r & 7)) * 8)];
    }

  const f32x4 fzero = {0.f, 0.f, 0.f, 0.f};
  f32x4 acc[4][4];
#pragma unroll
  for (int m = 0; m < 4; m++)
#pragma unroll
    for (int n = 0; n < 4; n++) acc[m][n] = fzero;

  const int nt = (kend - kbeg) >> 6;  // 32/32/22/22: even, >= 4

  u16x8 Aa[4], Ab[4];
  float2 RAg[8], RAu[8], RBg[8], RBu[8];

  // ---- prologue: tiles 0,1 -> regs; stage tile 0 -> buf0 ----
  LOADA(Aa, kbeg);        LOADB(RAg, RAu, kbeg);
  LOADA(Ab, kbeg + 64);   LOADB(RBg, RBu, kbeg + 64);
  WRITEA(Aa, 0);          CVTB(RAg, RAu, 0);
  PHASE_BAR();

  for (int u = 0; u < nt; u += 2) {
    const int k0 = kbeg + u * 64;
    // even half: compute buf0(tile u); stage tile u+1 -> buf1; load tile u+2 -> {Aa,RA}
    WRITEA(Ab, 8192);
    CVTB(RBg, RBu, 8192);
    if (u + 2 < nt) { LOADA(Aa, k0 + 128); LOADB(RAg, RAu, k0 + 128); }
    COMPUTE(0);
    PHASE_BAR();
    // odd half: compute buf1(tile u+1); stage tile u+2 -> buf0; load tile u+3 -> {Ab,RB}
    if (u + 2 < nt) {
      WRITEA(Aa, 0);
      CVTB(RAg, RAu, 0);
      if (u + 3 < nt) { LOADA(Ab, k0 + 192); LOADB(RBg, RBu, k0 + 192); }
      COMPUTE(8192);
      PHASE_BAR();
    } else {
      COMPUTE(8192);
    }
  }

  if constexpr (MODE < 2) {
#pragma unroll
    for (int m = 0; m < 4; m++) {
#pragma unroll
      for (int i = 0; i < 4; i++) {
        int rowslot = mtile * 128 + wm * 64 + m * 16 + (lane >> 4) * 4 + i;
        float rsc = 1.f;
        if constexpr (MODE == 1) rsc = wl[rowslot];  // padding slots: 0.0 (memset)
#pragma unroll
        for (int p = 0; p < 2; p++) {
          float g = acc[m][p][i];
          float u2 = acc[m][p + 2][i];
          float sv = g / (1.f + __expf(-g)) * u2 * rsc;
          int col = ntile * 64 + wn * 32 + p * 16 + (lane & 15);
          actout[(size_t)rowslot * IK + col] = f2bf(sv);
        }
      }
    }
  } else {
#pragma unroll
    for (int m = 0; m < 4; m++) {
#pragma unroll
      for (int i = 0; i < 4; i++) {
        int rowslot = mtile * 128 + wm * 64 + m * 16 + (lane >> 4) * 4 + i;
        int token = rowslot;
        if constexpr (MODE == 3) token = tl[rowslot];  // padding: token 0, acc==0
        float sc = 1.f;
        if constexpr (MODE == 2) sc = gate_sig[token];
        float* orow = out + (size_t)token * H_DIM + ntile * 128 + wn * 64 + (lane & 15);
#pragma unroll
        for (int nf = 0; nf < 4; nf++)
          atomicAdd(orow + nf * 16, acc[m][nf][i] * sc);
      }
    }
  }
}

extern "C" void kernel_launch(void* const* d_in, const int* in_sizes, int n_in,
                              void* d_out, int out_size, void* d_ws, size_t ws_size,
                              hipStream_t stream) {
  (void)in_sizes; (void)n_in; (void)out_size; (void)ws_size;
  const float* x    = (const float*)d_in[0];
  const float* wg   = (const float*)d_in[1];
  const float* wsg  = (const float*)d_in[2];
  const float* wsgu = (const float*)d_in[3];
  const float* wsd  = (const float*)d_in[4];
  const float* wegu = (const float*)d_in[5];
  const float* wed  = (const float*)d_in[6];
  float* out = (float*)d_out;

  char* ws = (char*)d_ws;
  unsigned short* xb   = (unsigned short*)ws;                                   // 4 MB
  unsigned short* acts = (unsigned short*)(ws + (4u << 20));                    // T*ISD bf16
  unsigned short* acte = (unsigned short*)(ws + (4u << 20) + 11534336u);        // E*T*IED bf16
  char* ctrl = ws + (4u << 20) + 11534336u + 23068672u;
  int* counts    = (int*)ctrl;
  int* tlist     = (int*)(ctrl + 256);
  float* wlist   = (float*)(ctrl + 256 + 32768);
  float* gate_sig = (float*)(ctrl + 256 + 65536);

  hipMemsetAsync(d_out, 0, (size_t)T_TOK * H_DIM * 4, stream);
  hipMemsetAsync(ctrl, 0, 256 + 65536, stream);

  k_cvt<<<dim3(2048), dim3(256), 0, stream>>>(x, xb);
  k_router<<<dim3(256), dim3(256), 0, stream>>>(x, wg, wsg, counts, tlist, wlist, gate_sig);
  k_mm<0><<<dim3(704), dim3(256), 0, stream>>>(xb, wsgu, acts, out, counts, tlist, wlist, gate_sig);
  k_mm<1><<<dim3(1408), dim3(256), 0, stream>>>(xb, wegu, acte, out, counts, tlist, wlist, gate_sig);
  k_mm<2><<<dim3(512), dim3(256), 0, stream>>>(acts, wsd, nullptr, out, counts, tlist, wlist, gate_sig);
  k_mm<3><<<dim3(1024), dim3(256), 0, stream>>>(acte, wed, nullptr, out, counts, tlist, wlist, gate_sig);
}

// Round 4
// 513.011 us; speedup vs baseline: 1.9820x; 1.9820x over previous
//
#include <hip/hip_runtime.h>
#include <hip/hip_bf16.h>
#include <stdint.h>

#define T_TOK 1024
#define H_DIM 2048
#define NEXP 8
#define IED 1408
#define ISD 5632

typedef __attribute__((ext_vector_type(8))) short s16x8;
typedef __attribute__((ext_vector_type(8))) unsigned short u16x8;
typedef __attribute__((ext_vector_type(4))) float f32x4;

__device__ __forceinline__ unsigned short f2bf(float f) {
  union { float f; unsigned u; } v; v.f = f;
  unsigned r = v.u + 0x7FFFu + ((v.u >> 16) & 1u);
  return (unsigned short)(r >> 16);
}

__device__ __forceinline__ void gload16(const void* g, void* l) {
  __builtin_amdgcn_global_load_lds(
      (const __attribute__((address_space(1))) unsigned int*)g,
      (__attribute__((address_space(3))) unsigned int*)l, 16, 0, 0);
}

// ---------------- fp32 -> bf16 convert for hidden states ----------------
extern "C" __global__ void __launch_bounds__(256) k_cvt(
    const float* __restrict__ x, unsigned short* __restrict__ xb) {
  int i = (blockIdx.x * 256 + threadIdx.x) * 4;
  float4 v = *(const float4*)(x + i);
  ushort4 o;
  o.x = f2bf(v.x); o.y = f2bf(v.y); o.z = f2bf(v.z); o.w = f2bf(v.w);
  *(ushort4*)(xb + i) = o;
}

// ---------------- router: logits, softmax, top-4, shared gate ----------------
extern "C" __global__ void __launch_bounds__(256) k_router(
    const float* __restrict__ x, const float* __restrict__ wg,
    const float* __restrict__ wsg, int* __restrict__ counts,
    int* __restrict__ tlist, float* __restrict__ wlist,
    float* __restrict__ gate_sig) {
  const int lane = threadIdx.x & 63;
  const int t = blockIdx.x * 4 + (threadIdx.x >> 6);
  const float* xr = x + (size_t)t * H_DIM;
  float acc[8];
#pragma unroll
  for (int e = 0; e < 8; e++) acc[e] = 0.f;
  float sg = 0.f;
  for (int h = lane; h < H_DIM; h += 64) {
    float xv = xr[h];
    float4 w0 = *(const float4*)(wg + h * 8);
    float4 w1 = *(const float4*)(wg + h * 8 + 4);
    acc[0] += xv * w0.x; acc[1] += xv * w0.y; acc[2] += xv * w0.z; acc[3] += xv * w0.w;
    acc[4] += xv * w1.x; acc[5] += xv * w1.y; acc[6] += xv * w1.z; acc[7] += xv * w1.w;
    sg += xv * wsg[h];
  }
#pragma unroll
  for (int d = 32; d >= 1; d >>= 1) {
#pragma unroll
    for (int e = 0; e < 8; e++) acc[e] += __shfl_xor(acc[e], d, 64);
    sg += __shfl_xor(sg, d, 64);
  }
  if (lane == 0) {
    float m = acc[0];
#pragma unroll
    for (int e = 1; e < 8; e++) m = fmaxf(m, acc[e]);
    float p[8], s = 0.f;
#pragma unroll
    for (int e = 0; e < 8; e++) { p[e] = __expf(acc[e] - m); s += p[e]; }
    float inv = 1.f / s;
    bool used[8];
#pragma unroll
    for (int e = 0; e < 8; e++) used[e] = false;
    for (int j = 0; j < 4; j++) {
      int be = 0; float bv = -1e30f;
#pragma unroll
      for (int e = 0; e < 8; e++)
        if (!used[e] && acc[e] > bv) { bv = acc[e]; be = e; }
      used[be] = true;
      int slot = atomicAdd(counts + be, 1);
      tlist[be * T_TOK + slot] = t;
      wlist[be * T_TOK + slot] = p[be] * inv;
    }
    gate_sig[t] = 1.f / (1.f + __expf(-sg));
  }
}

// ---------------- staging / compute macros ----------------
#define ISSUE_A(kk, OFFS)                                                 \
  do {                                                                    \
    _Pragma("unroll") for (int q = 0; q < 4; q++)                         \
        gload16(asrc[q] + (kk), adst[q] + (OFFS));                        \
  } while (0)

#define ISSUE_B(kk)                                                       \
  do {                                                                    \
    _Pragma("unroll") for (int i = 0; i < 8; i++) {                       \
      size_t ko = (size_t)((kk) + bkset + i) * (size_t)ldb;               \
      RBg[i] = *(const float2*)(B0 + ko + bn);                            \
      RBu[i] = *(const float2*)(B1 + ko + bn);                            \
    }                                                                     \
  } while (0)

#define CVTB(OFFS)                                                        \
  do {                                                                    \
    _Pragma("unroll") for (int jj = 0; jj < 2; jj++) {                    \
      u16x8 pg, pu;                                                       \
      _Pragma("unroll") for (int i = 0; i < 8; i++) {                     \
        pg[i] = f2bf(jj ? RBg[i].y : RBg[i].x);                           \
        pu[i] = f2bf(jj ? RBu[i].y : RBu[i].x);                           \
      }                                                                   \
      *(u16x8*)(bwr[0][jj] + (OFFS)) = pg;                                \
      *(u16x8*)(bwr[1][jj] + (OFFS)) = pu;                                \
    }                                                                     \
  } while (0)

#define COMPUTE(OFFS)                                                     \
  do {                                                                    \
    const unsigned short* ab = a_lds + (OFFS);                            \
    const unsigned short* bb = b_lds + (OFFS);                            \
    __builtin_amdgcn_s_setprio(1);                                        \
    _Pragma("unroll") for (int ks = 0; ks < 2; ks++) {                    \
      int kc = ks * 4 + (lane >> 4);                                      \
      s16x8 afr[4];                                                       \
      _Pragma("unroll") for (int m = 0; m < 4; m++) {                     \
        int r = wm * 64 + m * 16 + (lane & 15);                           \
        afr[m] = *(const s16x8*)&ab[r * 64 + ((kc ^ (r & 7)) * 8)];       \
      }                                                                   \
      _Pragma("unroll") for (int nf = 0; nf < 4; nf++) {                  \
        int rb_;                                                          \
        if constexpr (MODE < 2) rb_ = wn * 32 + (nf & 1) * 16 + (nf >> 1) * 64; \
        else rb_ = wn * 64 + nf * 16;                                     \
        rb_ += (lane & 15);                                               \
        s16x8 bfr = *(const s16x8*)&bb[rb_ * 64 + ((kc ^ (rb_ & 7)) * 8)]; \
        _Pragma("unroll") for (int m = 0; m < 4; m++)                     \
            acc[m][nf] = __builtin_amdgcn_mfma_f32_16x16x32_bf16(         \
                afr[m], bfr, acc[m][nf], 0, 0, 0);                        \
      }                                                                   \
    }                                                                     \
    __builtin_amdgcn_s_setprio(0);                                        \
  } while (0)

// ---------------- unified MFMA GEMM, counted-vmcnt pipelined, XCD-grouped ----------------
// MODE 0: shared gu   MODE 1: expert gu   MODE 2: shared down   MODE 3: expert down
template <int MODE>
__global__ void __launch_bounds__(256, 2) k_mm(
    const unsigned short* __restrict__ Abase, const float* __restrict__ Bbase,
    unsigned short* __restrict__ actout, float* __restrict__ out,
    const int* __restrict__ counts, const int* __restrict__ tlist,
    const float* __restrict__ wlist, const float* __restrict__ gate_sig) {
  const int tid = threadIdx.x;
  const int lane = tid & 63;
  const int wid = tid >> 6;
  const int wm = wid >> 1, wn = wid & 1;

  // XCD-grouped decode: xcd = b%8 owns P/8 consecutive B-panels; mtile fastest.
  constexpr int P = (MODE == 0) ? 88 : (MODE == 1) ? 176 : (MODE == 2) ? 64 : 128;
  const int b = blockIdx.x;
  const int xcd = b & 7;
  const int j = b >> 3;
  const int panel = xcd * (P >> 3) + (j >> 3);
  const int mtile = j & 7;
  int ntile = 0, z = 0, e = 0;
  if constexpr (MODE == 0) { ntile = panel; }
  else if constexpr (MODE == 1) { e = panel & 7; ntile = panel >> 3; }
  else if constexpr (MODE == 2) { ntile = panel >> 2; z = panel & 3; }
  else { e = panel & 7; ntile = panel >> 3; }

  int count = T_TOK, kbeg = 0, kend = 0, lda = 0, ldb = 0, IK = 0;
  const unsigned short* A = Abase;
  const float* B0 = nullptr; const float* B1 = nullptr;
  const int* tl = nullptr; const float* wl = nullptr;

  if constexpr (MODE == 0) {
    lda = H_DIM; kend = H_DIM; ldb = 2 * ISD; IK = ISD;
    B0 = Bbase + ntile * 64; B1 = Bbase + ISD + ntile * 64;
  } else if constexpr (MODE == 1) {
    count = counts[e];
    if (mtile * 128 >= count) return;
    lda = H_DIM; kend = H_DIM; ldb = 2 * IED; IK = IED;
    const float* Bw = Bbase + (size_t)e * H_DIM * (2 * IED);
    B0 = Bw + ntile * 64; B1 = Bw + IED + ntile * 64;
    tl = tlist + e * T_TOK; wl = wlist + e * T_TOK;
    actout += (size_t)e * T_TOK * IED;
  } else if constexpr (MODE == 2) {
    lda = ISD; kbeg = z * 1408; kend = kbeg + 1408; ldb = H_DIM; IK = H_DIM;
    B0 = Bbase + ntile * 128; B1 = Bbase + ntile * 128 + 64;
  } else {
    count = counts[e];
    if (mtile * 128 >= count) return;
    lda = IED; kend = IED; ldb = H_DIM; IK = H_DIM;
    B0 = Bbase + (size_t)e * IED * H_DIM + ntile * 128;
    B1 = B0 + 64;
    A = Abase + (size_t)e * T_TOK * IED;
    tl = tlist + e * T_TOK;
  }

  __shared__ unsigned short a_lds[2 * 8192];
  __shared__ unsigned short b_lds[2 * 8192];

  // A: global_load_lds with PRE-SWIZZLED global source, linear LDS dest.
  // lds[row][c] holds A[row][c ^ (row&7)] (8-elem chunks); read applies same XOR.
  const unsigned short* asrc[4];
  unsigned short* adst[4];
#pragma unroll
  for (int q = 0; q < 4; q++) {
    int row = wid * 32 + q * 8 + (lane >> 3);
    int rowg = mtile * 128 + row;
    int arow = rowg;
    if constexpr (MODE == 1) arow = tl[rowg];  // padding slots hold 0 (memset)
    int kc = (lane & 7) ^ ((lane >> 3) & 7);   // = (lane&7) ^ (row&7)
    asrc[q] = A + (size_t)arow * lda + kc * 8;
    adst[q] = &a_lds[(wid * 4 + q) * 512];
  }

  // B staging geometry: thread covers n = bn, bn+1 (per half) x k = bkset..bkset+7
  const int bn = (tid & 31) * 2;
  const int bkset = ((tid >> 5) & 7) * 8;
  const int bkc = (tid >> 5) & 7;
  unsigned short* bwr[2][2];
#pragma unroll
  for (int h = 0; h < 2; h++)
#pragma unroll
    for (int jj = 0; jj < 2; jj++) {
      int r = h * 64 + bn + jj;
      bwr[h][jj] = &b_lds[r * 64 + ((bkc ^ (r & 7)) * 8)];
    }

  const f32x4 fzero = {0.f, 0.f, 0.f, 0.f};
  f32x4 acc[4][4];
#pragma unroll
  for (int m = 0; m < 4; m++)
#pragma unroll
    for (int n = 0; n < 4; n++) acc[m][n] = fzero;

  const int nt = (kend - kbeg) >> 6;  // 32 / 32 / 22 / 22
  float2 RBg[8], RBu[8];

  // ---- prologue ----
  ISSUE_B(kbeg);          // B(0) -> regs            [16 vmem]
  ISSUE_A(kbeg, 0);       // A(0) -> buf0            [4 vmem]
  CVTB(0);                // compiler waits B(0) regs; ds_write buf0
  ISSUE_B(kbeg + 64);     // B(1) -> regs            [16 vmem in flight]
  __builtin_amdgcn_sched_barrier(0);
  asm volatile("s_waitcnt vmcnt(16)" ::: "memory");  // A(0) landed; B(1) in flight
  asm volatile("s_waitcnt lgkmcnt(0)" ::: "memory");
  __builtin_amdgcn_s_barrier();
  __builtin_amdgcn_sched_barrier(0);

  for (int u = 0; u < nt; ++u) {
    const int cur = (u & 1) * 8192;
    const int nxt = cur ^ 8192;
    const int k0 = kbeg + u * 64;
    const bool haveN1 = (u + 1 < nt);
    const bool haveN2 = (u + 2 < nt);
    if (haveN1) {
      ISSUE_A(k0 + 64, nxt);                 // A(u+1) -> nxt   [4]
      CVTB(nxt);                             // B(u+1) regs -> nxt (compiler-counted wait)
      if (haveN2) ISSUE_B(k0 + 128);         // B(u+2) -> regs  [16]
    }
    COMPUTE(cur);
    if (haveN1) {
      __builtin_amdgcn_sched_barrier(0);
      if (haveN2)
        asm volatile("s_waitcnt vmcnt(16)" ::: "memory");  // A(u+1) done, B(u+2) in flight
      else
        asm volatile("s_waitcnt vmcnt(0)" ::: "memory");   // tail: drain A(u+1)
      asm volatile("s_waitcnt lgkmcnt(0)" ::: "memory");
      __builtin_amdgcn_s_barrier();
      __builtin_amdgcn_sched_barrier(0);
    }
  }

  if constexpr (MODE < 2) {
#pragma unroll
    for (int m = 0; m < 4; m++) {
#pragma unroll
      for (int i = 0; i < 4; i++) {
        int rowslot = mtile * 128 + wm * 64 + m * 16 + (lane >> 4) * 4 + i;
        float rsc = 1.f;
        if constexpr (MODE == 1) rsc = wl[rowslot];  // padding slots: 0.0 (memset)
#pragma unroll
        for (int p = 0; p < 2; p++) {
          float g = acc[m][p][i];
          float u2 = acc[m][p + 2][i];
          float sv = g / (1.f + __expf(-g)) * u2 * rsc;
          int col = ntile * 64 + wn * 32 + p * 16 + (lane & 15);
          actout[(size_t)rowslot * IK + col] = f2bf(sv);
        }
      }
    }
  } else {
#pragma unroll
    for (int m = 0; m < 4; m++) {
#pragma unroll
      for (int i = 0; i < 4; i++) {
        int rowslot = mtile * 128 + wm * 64 + m * 16 + (lane >> 4) * 4 + i;
        int token = rowslot;
        if constexpr (MODE == 3) token = tl[rowslot];  // padding: token 0, acc==0
        float sc = 1.f;
        if constexpr (MODE == 2) sc = gate_sig[token];
        float* orow = out + (size_t)token * H_DIM + ntile * 128 + wn * 64 + (lane & 15);
#pragma unroll
        for (int nf = 0; nf < 4; nf++)
          atomicAdd(orow + nf * 16, acc[m][nf][i] * sc);
      }
    }
  }
}

extern "C" void kernel_launch(void* const* d_in, const int* in_sizes, int n_in,
                              void* d_out, int out_size, void* d_ws, size_t ws_size,
                              hipStream_t stream) {
  (void)in_sizes; (void)n_in; (void)out_size; (void)ws_size;
  const float* x    = (const float*)d_in[0];
  const float* wg   = (const float*)d_in[1];
  const float* wsg  = (const float*)d_in[2];
  const float* wsgu = (const float*)d_in[3];
  const float* wsd  = (const float*)d_in[4];
  const float* wegu = (const float*)d_in[5];
  const float* wed  = (const float*)d_in[6];
  float* out = (float*)d_out;

  char* ws = (char*)d_ws;
  unsigned short* xb   = (unsigned short*)ws;                                   // 4 MB
  unsigned short* acts = (unsigned short*)(ws + (4u << 20));                    // T*ISD bf16
  unsigned short* acte = (unsigned short*)(ws + (4u << 20) + 11534336u);        // E*T*IED bf16
  char* ctrl = ws + (4u << 20) + 11534336u + 23068672u;
  int* counts    = (int*)ctrl;
  int* tlist     = (int*)(ctrl + 256);
  float* wlist   = (float*)(ctrl + 256 + 32768);
  float* gate_sig = (float*)(ctrl + 256 + 65536);

  hipMemsetAsync(d_out, 0, (size_t)T_TOK * H_DIM * 4, stream);
  hipMemsetAsync(ctrl, 0, 256 + 65536, stream);

  k_cvt<<<dim3(2048), dim3(256), 0, stream>>>(x, xb);
  k_router<<<dim3(256), dim3(256), 0, stream>>>(x, wg, wsg, counts, tlist, wlist, gate_sig);
  k_mm<0><<<dim3(704), dim3(256), 0, stream>>>(xb, wsgu, acts, out, counts, tlist, wlist, gate_sig);
  k_mm<1><<<dim3(1408), dim3(256), 0, stream>>>(xb, wegu, acte, out, counts, tlist, wlist, gate_sig);
  k_mm<2><<<dim3(512), dim3(256), 0, stream>>>(acts, wsd, nullptr, out, counts, tlist, wlist, gate_sig);
  k_mm<3><<<dim3(1024), dim3(256), 0, stream>>>(acte, wed, nullptr, out, counts, tlist, wlist, gate_sig);
}

// Round 6
// 467.807 us; speedup vs baseline: 2.1735x; 1.0966x over previous
//
#include <hip/hip_runtime.h>
#include <hip/hip_bf16.h>
#include <stdint.h>

#define T_TOK 1024
#define H_DIM 2048
#define NEXP 8
#define IED 1408
#define ISD 5632

typedef __attribute__((ext_vector_type(8))) short s16x8;
typedef __attribute__((ext_vector_type(8))) unsigned short u16x8;
typedef __attribute__((ext_vector_type(4))) float f32x4;

// bank-quad-balanced chunk swizzle (period 16 rows)
#define SWZ(r) (((r) ^ ((r) >> 2)) & 3)

__device__ __forceinline__ unsigned short f2bf(float f) {
  union { float f; unsigned u; } v; v.f = f;
  unsigned r = v.u + 0x7FFFu + ((v.u >> 16) & 1u);
  return (unsigned short)(r >> 16);
}

__device__ __forceinline__ void gload16(const void* g, void* l) {
  __builtin_amdgcn_global_load_lds(
      (const __attribute__((address_space(1))) unsigned int*)g,
      (__attribute__((address_space(3))) unsigned int*)l, 16, 0, 0);
}

// ---------------- router + x->bf16 convert (fused) ----------------
extern "C" __global__ void __launch_bounds__(256) k_router(
    const float* __restrict__ x, const float* __restrict__ wg,
    const float* __restrict__ wsg, unsigned short* __restrict__ xb,
    int* __restrict__ counts, int* __restrict__ tlist,
    float* __restrict__ wlist, float* __restrict__ gate_sig) {
  const int tid = threadIdx.x;
  const int bb = blockIdx.x;
#pragma unroll
  for (int it = 0; it < 8; it++) {
    int i = bb * 8192 + it * 1024 + tid * 4;
    float4 v = *(const float4*)(x + i);
    ushort4 o;
    o.x = f2bf(v.x); o.y = f2bf(v.y); o.z = f2bf(v.z); o.w = f2bf(v.w);
    *(ushort4*)(xb + i) = o;
  }
  const int lane = tid & 63;
  const int t = bb * 4 + (tid >> 6);
  const float* xr = x + (size_t)t * H_DIM;
  float acc[8];
#pragma unroll
  for (int e = 0; e < 8; e++) acc[e] = 0.f;
  float sg = 0.f;
  for (int h = lane; h < H_DIM; h += 64) {
    float xv = xr[h];
    float4 w0 = *(const float4*)(wg + h * 8);
    float4 w1 = *(const float4*)(wg + h * 8 + 4);
    acc[0] += xv * w0.x; acc[1] += xv * w0.y; acc[2] += xv * w0.z; acc[3] += xv * w0.w;
    acc[4] += xv * w1.x; acc[5] += xv * w1.y; acc[6] += xv * w1.z; acc[7] += xv * w1.w;
    sg += xv * wsg[h];
  }
#pragma unroll
  for (int d = 32; d >= 1; d >>= 1) {
#pragma unroll
    for (int e = 0; e < 8; e++) acc[e] += __shfl_xor(acc[e], d, 64);
    sg += __shfl_xor(sg, d, 64);
  }
  if (lane == 0) {
    float m = acc[0];
#pragma unroll
    for (int e = 1; e < 8; e++) m = fmaxf(m, acc[e]);
    float p[8], s = 0.f;
#pragma unroll
    for (int e = 0; e < 8; e++) { p[e] = __expf(acc[e] - m); s += p[e]; }
    float inv = 1.f / s;
    bool used[8];
#pragma unroll
    for (int e = 0; e < 8; e++) used[e] = false;
    for (int j = 0; j < 4; j++) {
      int be = 0; float bv = -1e30f;
#pragma unroll
      for (int e = 0; e < 8; e++)
        if (!used[e] && acc[e] > bv) { bv = acc[e]; be = e; }
      used[be] = true;
      int slot = atomicAdd(counts + be, 1);
      tlist[be * T_TOK + slot] = t;
      wlist[be * T_TOK + slot] = p[be] * inv;
    }
    gate_sig[t] = 1.f / (1.f + __expf(-sg));
  }
}

// ---------------- staging / compute macros (BK=32) ----------------
#define ISSUE_A(kk, OFFS)                                                 \
  do {                                                                    \
    _Pragma("unroll") for (int q = 0; q < 2; q++)                         \
        gload16(asrc[q] + (kk), adst[q] + (OFFS));                        \
    __builtin_amdgcn_sched_barrier(0);                                    \
  } while (0)

#define ISSUE_B(kk)                                                       \
  do {                                                                    \
    _Pragma("unroll") for (int i = 0; i < 8; i++)                         \
        RB[i] = *(const float2*)(Bh + (size_t)((kk) + bks + i) * (size_t)ldb + bn); \
  } while (0)

#define CVTB(OFFS)                                                        \
  do {                                                                    \
    _Pragma("unroll") for (int jj = 0; jj < 2; jj++) {                    \
      u16x8 pk;                                                           \
      _Pragma("unroll") for (int i = 0; i < 8; i++)                       \
          pk[i] = f2bf(jj ? RB[i].y : RB[i].x);                           \
      *(u16x8*)(bwr[jj] + (OFFS)) = pk;                                   \
    }                                                                     \
  } while (0)

#define COMPUTE(OFFS)                                                     \
  do {                                                                    \
    const unsigned short* ab = a_lds + (OFFS);                            \
    const unsigned short* bb2 = b_lds + (OFFS);                           \
    __builtin_amdgcn_s_setprio(1);                                        \
    {                                                                     \
      const int kc = lane >> 4;                                           \
      s16x8 afr[4];                                                       \
      _Pragma("unroll") for (int m = 0; m < 4; m++) {                     \
        int r = wm * 64 + m * 16 + (lane & 15);                           \
        afr[m] = *(const s16x8*)&ab[r * 32 + ((kc ^ SWZ(r)) * 8)];        \
      }                                                                   \
      _Pragma("unroll") for (int nf = 0; nf < 4; nf++) {                  \
        int rb_;                                                          \
        if constexpr (DOWN) rb_ = wn * 64 + nf * 16;                      \
        else rb_ = wn * 32 + (nf & 1) * 16 + (nf >> 1) * 64;              \
        rb_ += (lane & 15);                                               \
        s16x8 bfr = *(const s16x8*)&bb2[rb_ * 32 + ((kc ^ SWZ(rb_)) * 8)]; \
        _Pragma("unroll") for (int m = 0; m < 4; m++)                     \
            acc[m][nf] = __builtin_amdgcn_mfma_f32_16x16x32_bf16(         \
                afr[m], bfr, acc[m][nf], 0, 0, 0);                        \
      }                                                                   \
    }                                                                     \
    __builtin_amdgcn_s_setprio(0);                                        \
  } while (0)

// ---------------- fused MFMA GEMM pair, BK=32, counted-vmcnt pipeline ----------------
// DOWN=0: shared-gu (blocks 0..703) + expert-gu (704..2111), K=2048 (nt=64)
// DOWN=1: shared-down splitK4 (0..511) + expert-down (512..1535), K=1408 (nt=44)
template <int DOWN>
__global__ void __launch_bounds__(256, 4) k_mm(
    const unsigned short* __restrict__ A_sh, const unsigned short* __restrict__ A_ex,
    const float* __restrict__ B_sh, const float* __restrict__ B_ex,
    unsigned short* __restrict__ act_sh, unsigned short* __restrict__ act_ex,
    float* __restrict__ out,
    const int* __restrict__ counts, const int* __restrict__ tlist,
    const float* __restrict__ wlist, const float* __restrict__ gate_sig) {
  const int tid = threadIdx.x;
  const int lane = tid & 63;
  const int wid = tid >> 6;
  const int wm = wid >> 1, wn = wid & 1;

  constexpr int SHBLK = DOWN ? 512 : 704;
  const int b0 = blockIdx.x;
  const bool ex = b0 >= SHBLK;
  const int b = ex ? b0 - SHBLK : b0;
  const int xcd = b & 7;
  const int j = b >> 3;
  const int mtile = j & 7;
  int e = 0, ntile = 0, z = 0;
  if constexpr (!DOWN) {
    if (!ex) ntile = xcd * 11 + (j >> 3);
    else { int p = xcd * 22 + (j >> 3); e = p & 7; ntile = p >> 3; }
  } else {
    if (!ex) { int p = xcd * 8 + (j >> 3); ntile = p >> 2; z = p & 3; }
    else { int p = xcd * 16 + (j >> 3); e = p & 7; ntile = p >> 3; }
  }

  int lda, ldb, IK = 0, kbeg = 0, count = T_TOK;
  const unsigned short* A;
  const float* B0; const float* B1;
  const int* tlA = nullptr;   // A-row gather (gu-expert ONLY)
  const int* tlO = nullptr;   // output token scatter (down-expert ONLY)
  const float* wl = nullptr;
  unsigned short* actout = nullptr;

  if constexpr (!DOWN) {
    lda = H_DIM;
    if (!ex) {
      ldb = 2 * ISD; IK = ISD; A = A_sh; actout = act_sh;
      B0 = B_sh + ntile * 64; B1 = B_sh + ISD + ntile * 64;
    } else {
      count = counts[e];
      if (mtile * 128 >= count) return;
      ldb = 2 * IED; IK = IED; A = A_sh;
      const float* Bw = B_ex + (size_t)e * H_DIM * (2 * IED);
      B0 = Bw + ntile * 64; B1 = Bw + IED + ntile * 64;
      tlA = tlist + e * T_TOK; wl = wlist + e * T_TOK;
      actout = act_ex + (size_t)e * T_TOK * IED;
    }
  } else {
    ldb = H_DIM;
    if (!ex) {
      lda = ISD; kbeg = z * 1408; A = A_sh;
      B0 = B_sh + ntile * 128; B1 = B0 + 64;
    } else {
      count = counts[e];
      if (mtile * 128 >= count) return;
      lda = IED; A = A_ex + (size_t)e * T_TOK * IED;  // rows indexed by SLOT, no gather
      B0 = B_ex + (size_t)e * IED * H_DIM + ntile * 128; B1 = B0 + 64;
      tlO = tlist + e * T_TOK;
    }
  }
  const int nt = DOWN ? 44 : 64;

  __shared__ unsigned short a_lds[2 * 4096];  // [buf][128 rows][4 chunks of 8]
  __shared__ unsigned short b_lds[2 * 4096];

  // A: global_load_lds, pre-swizzled source chunk, linear LDS dest.
  // LDS[r][c] holds global chunk c ^ SWZ(r).
  const unsigned short* asrc[2];
  unsigned short* adst[2];
#pragma unroll
  for (int q = 0; q < 2; q++) {
    int row = wid * 32 + q * 16 + (lane >> 2);
    int rowg = mtile * 128 + row;
    int arow = rowg;
    if (tlA) arow = tlA[rowg];  // padding slots hold 0 (memset)
    asrc[q] = A + (size_t)arow * lda + (((lane & 3) ^ SWZ(row)) * 8);
    adst[q] = &a_lds[(wid * 32 + q * 16) * 32];
  }

  // B staging: half = tid>>7; 2 cols bn,bn+1; k-chunk kg.
  const int half = tid >> 7;
  const int bn = (tid & 31) * 2;
  const int kg = (tid >> 5) & 3;
  const int bks = kg * 8;
  const float* Bh = half ? B1 : B0;
  unsigned short* bwr[2];
#pragma unroll
  for (int jj = 0; jj < 2; jj++) {
    int r = half * 64 + bn + jj;
    bwr[jj] = &b_lds[r * 32 + ((kg ^ SWZ(r)) * 8)];
  }

  const f32x4 fzero = {0.f, 0.f, 0.f, 0.f};
  f32x4 acc[4][4];
#pragma unroll
  for (int m = 0; m < 4; m++)
#pragma unroll
    for (int n = 0; n < 4; n++) acc[m][n] = fzero;

  float2 RB[8];

  // ---- prologue ----
  ISSUE_B(kbeg);           // B(0) -> regs   [8 vmem]
  ISSUE_A(kbeg, 0);        // A(0) -> buf0   [2 vmem] (order pinned)
  CVTB(0);                 // compiler waits vmcnt(2); ds_write buf0
  ISSUE_B(kbeg + 32);      // B(1) -> regs   [8 in flight]
  __builtin_amdgcn_sched_barrier(0);
  asm volatile("s_waitcnt vmcnt(8)" ::: "memory");   // A(0) landed; B(1) in flight
  asm volatile("s_waitcnt lgkmcnt(0)" ::: "memory");
  __builtin_amdgcn_s_barrier();
  __builtin_amdgcn_sched_barrier(0);

  for (int u = 0; u < nt; ++u) {
    const int cur = (u & 1) * 4096;
    const int nxt = cur ^ 4096;
    const int k0 = kbeg + u * 32;
    const bool haveN1 = (u + 1 < nt);
    const bool haveN2 = (u + 2 < nt);
    if (haveN1) {
      ISSUE_A(k0 + 32, nxt);            // A(u+1) -> nxt  [2] (order pinned)
      CVTB(nxt);                        // B(u+1) regs -> nxt (compiler waits vmcnt(2))
      if (haveN2) ISSUE_B(k0 + 64);     // B(u+2) -> regs [8]
    }
    COMPUTE(cur);
    if (haveN1) {
      __builtin_amdgcn_sched_barrier(0);
      if (haveN2)
        asm volatile("s_waitcnt vmcnt(8)" ::: "memory");  // drain A(u+1); B(u+2) in flight
      else
        asm volatile("s_waitcnt vmcnt(0)" ::: "memory");
      asm volatile("s_waitcnt lgkmcnt(0)" ::: "memory");
      __builtin_amdgcn_s_barrier();
      __builtin_amdgcn_sched_barrier(0);
    }
  }

  if constexpr (!DOWN) {
#pragma unroll
    for (int m = 0; m < 4; m++) {
#pragma unroll
      for (int i = 0; i < 4; i++) {
        int rowslot = mtile * 128 + wm * 64 + m * 16 + (lane >> 4) * 4 + i;
        float rsc = 1.f;
        if (wl) rsc = wl[rowslot];  // padding slots: 0.0 (memset)
#pragma unroll
        for (int p = 0; p < 2; p++) {
          float g = acc[m][p][i];
          float u2 = acc[m][p + 2][i];
          float sv = g / (1.f + __expf(-g)) * u2 * rsc;
          int col = ntile * 64 + wn * 32 + p * 16 + (lane & 15);
          actout[(size_t)rowslot * IK + col] = f2bf(sv);
        }
      }
    }
  } else {
#pragma unroll
    for (int m = 0; m < 4; m++) {
#pragma unroll
      for (int i = 0; i < 4; i++) {
        int rowslot = mtile * 128 + wm * 64 + m * 16 + (lane >> 4) * 4 + i;
        int token = rowslot;
        if (tlO) token = tlO[rowslot];  // padding: token 0, acc==0
        float sc = ex ? 1.f : gate_sig[token];
        float* orow = out + (size_t)token * H_DIM + ntile * 128 + wn * 64 + (lane & 15);
#pragma unroll
        for (int nf = 0; nf < 4; nf++)
          atomicAdd(orow + nf * 16, acc[m][nf][i] * sc);
      }
    }
  }
}

extern "C" void kernel_launch(void* const* d_in, const int* in_sizes, int n_in,
                              void* d_out, int out_size, void* d_ws, size_t ws_size,
                              hipStream_t stream) {
  (void)in_sizes; (void)n_in; (void)out_size; (void)ws_size;
  const float* x    = (const float*)d_in[0];
  const float* wg   = (const float*)d_in[1];
  const float* wsg  = (const float*)d_in[2];
  const float* wsgu = (const float*)d_in[3];
  const float* wsd  = (const float*)d_in[4];
  const float* wegu = (const float*)d_in[5];
  const float* wed  = (const float*)d_in[6];
  float* out = (float*)d_out;

  char* ws = (char*)d_ws;
  unsigned short* xb   = (unsigned short*)ws;                                   // 4 MB
  unsigned short* acts = (unsigned short*)(ws + (4u << 20));                    // T*ISD bf16
  unsigned short* acte = (unsigned short*)(ws + (4u << 20) + 11534336u);        // E*T*IED bf16
  char* ctrl = ws + (4u << 20) + 11534336u + 23068672u;
  int* counts    = (int*)ctrl;
  int* tlist     = (int*)(ctrl + 256);
  float* wlist   = (float*)(ctrl + 256 + 32768);
  float* gate_sig = (float*)(ctrl + 256 + 65536);

  hipMemsetAsync(d_out, 0, (size_t)T_TOK * H_DIM * 4, stream);
  hipMemsetAsync(ctrl, 0, 256 + 65536, stream);

  k_router<<<dim3(256), dim3(256), 0, stream>>>(x, wg, wsg, xb, counts, tlist, wlist, gate_sig);
  k_mm<0><<<dim3(2112), dim3(256), 0, stream>>>(xb, xb, wsgu, wegu, acts, acte, nullptr,
                                                counts, tlist, wlist, gate_sig);
  k_mm<1><<<dim3(1536), dim3(256), 0, stream>>>(acts, acte, wsd, wed, nullptr, nullptr, out,
                                                counts, tlist, wlist, gate_sig);
}